// Round 2
// baseline (240.452 us; speedup 1.0000x reference)
//
#include <hip/hip_runtime.h>

// y = g(x) + x, g = W2^T relu(W1^T relu(x*W0+b0)+b1) + b2 is piecewise-linear
// in the scalar x. 2048-bin chord LUT over [-8,8] (bin width 1/128; kink-bin
// chord error ~0.01 << 0.115 threshold). Index CLAMPED: edge bins extrapolate
// the tail lines (g is linear in the tails); input is N(0,1) so clamping never
// fires on real data.
//
// Revision history:
//  234.6us: AoS f32x2 LUT, x2 unroll, NT load+store
//  237.8us: SoA LUT (s+1 folds +x residual), x2 unroll, plain stores  [noise]
//  this:    x4 unroll -- 4 NT loads in flight per wave before any compute
//           (store completion no longer gates the next iteration's vmcnt
//           wait), NT stores restored. SoA LDS kept: two ds_read_b32 (~2-way
//           random aliasing, free) vs one ds_read_b64 (~8-way).

#define NB       2048
#define LUT_LO   (-8.0f)
#define LUT_INVW (128.0f)          // NB / (HI-LO)
#define LUT_BINW (0.0078125f)      // (HI-LO)/NB

typedef float f32x4 __attribute__((ext_vector_type(4)));

__device__ __forceinline__ float mlp_g(float xe,
    const float* w0, const float* b0, const float* w1,
    const float* b1, const float* w2, float b2)
{
    float h0[8];
#pragma unroll
    for (int j = 0; j < 8; ++j)
        h0[j] = fmaxf(fmaf(xe, w0[j], b0[j]), 0.0f);
    float acc = b2;
#pragma unroll
    for (int k = 0; k < 8; ++k) {
        float t = b1[k];
#pragma unroll
        for (int j = 0; j < 8; ++j)
            t = fmaf(h0[j], w1[j * 8 + k], t);
        acc = fmaf(fmaxf(t, 0.0f), w2[k], acc);
    }
    return acc;
}

// ws layout: lut[0..NB)   = slope+1  (s1)   y = fmaf(s1, x, c)
//            lut[NB..2NB) = intercept (c)
__global__ __launch_bounds__(256) void build_lut_kernel(
    const float* __restrict__ W0p, const float* __restrict__ B0p,
    const float* __restrict__ W1p, const float* __restrict__ B1p,
    const float* __restrict__ W2p, const float* __restrict__ B2p,
    float* __restrict__ lut)
{
    int i = blockIdx.x * blockDim.x + threadIdx.x;
    if (i >= NB) return;
    float w0[8], b0[8], b1v[8], w2[8], w1[64];
#pragma unroll
    for (int j = 0; j < 8; ++j) {
        w0[j] = W0p[j]; b0[j] = B0p[j]; b1v[j] = B1p[j]; w2[j] = W2p[j];
    }
#pragma unroll
    for (int j = 0; j < 64; ++j) w1[j] = W1p[j];
    const float b2 = B2p[0];

    float x0 = LUT_LO + (float)i * LUT_BINW;
    float x1 = x0 + LUT_BINW;
    float g0 = mlp_g(x0, w0, b0, w1, b1v, w2, b2);
    float g1 = mlp_g(x1, w0, b0, w1, b1v, w2, b2);
    float s  = (g1 - g0) * LUT_INVW;
    lut[i]      = s + 1.0f;             // slope with +x residual folded in
    lut[i + NB] = fmaf(-s, x0, g0);     // intercept
}

__global__ __launch_bounds__(256) void mlp_lut_kernel(
    const float* __restrict__ x,
    const float* __restrict__ lut_g,
    float* __restrict__ out, int n4)
{
    __shared__ float slut[2 * NB];   // [0,NB): s1, [NB,2NB): c -- 16 KiB
    {
        const f32x4* g4 = (const f32x4*)lut_g;
        f32x4* s4 = (f32x4*)slut;
        for (int j = threadIdx.x; j < (2 * NB) / 4; j += 256)
            s4[j] = g4[j];
    }
    __syncthreads();

    const f32x4* __restrict__ x4 = (const f32x4*)x;
    f32x4* __restrict__ o4 = (f32x4*)out;

    const int T = gridDim.x * blockDim.x;    // total threads
    // n4 = 16*T for the bench shape (2^23 float4, 524288 threads):
    // 4 macro-iterations, 4 float4 in flight each.
    for (int i = blockIdx.x * blockDim.x + threadIdx.x; i < n4; i += 4 * T) {
        f32x4 v0, v1, v2, v3;
        const int i1 = i + T, i2 = i + 2 * T, i3 = i + 3 * T;
        v0 = __builtin_nontemporal_load(&x4[i]);
        if (i1 < n4) v1 = __builtin_nontemporal_load(&x4[i1]);
        if (i2 < n4) v2 = __builtin_nontemporal_load(&x4[i2]);
        if (i3 < n4) v3 = __builtin_nontemporal_load(&x4[i3]);

#define PROC(vv, ii)                                                     \
        {                                                                \
            float r_[4] = {(vv).x, (vv).y, (vv).z, (vv).w};              \
            float y_[4];                                                 \
            _Pragma("unroll")                                            \
            for (int e = 0; e < 4; ++e) {                                \
                float xe = r_[e];                                        \
                int idx = (int)fmaf(xe, LUT_INVW, -LUT_LO * LUT_INVW);   \
                idx = min(max(idx, 0), NB - 1);      /* v_med3_i32 */    \
                float s1 = slut[idx];                /* ds_read_b32 */   \
                float c  = slut[idx + NB];           /* +offset:8192 */  \
                y_[e] = fmaf(s1, xe, c);             /* g(x) + x */      \
            }                                                            \
            f32x4 o_; o_.x = y_[0]; o_.y = y_[1]; o_.z = y_[2];          \
            o_.w = y_[3];                                                \
            __builtin_nontemporal_store(o_, &o4[ii]);                    \
        }

        PROC(v0, i);
        if (i1 < n4) PROC(v1, i1);
        if (i2 < n4) PROC(v2, i2);
        if (i3 < n4) PROC(v3, i3);
#undef PROC
    }
}

extern "C" void kernel_launch(void* const* d_in, const int* in_sizes, int n_in,
                              void* d_out, int out_size, void* d_ws, size_t ws_size,
                              hipStream_t stream) {
    const float* x  = (const float*)d_in[0];
    const float* W0 = (const float*)d_in[1];
    const float* b0 = (const float*)d_in[2];
    const float* W1 = (const float*)d_in[3];
    const float* b1 = (const float*)d_in[4];
    const float* W2 = (const float*)d_in[5];
    const float* b2 = (const float*)d_in[6];
    float* out = (float*)d_out;

    const int n4 = out_size / 4;   // bytes/4 -> float count; /4 via f32x4 view
    float* lut = (float*)d_ws;     // 16 KiB scratch, SoA

    hipLaunchKernelGGL(build_lut_kernel, dim3(NB / 256), dim3(256), 0, stream,
                       W0, b0, W1, b1, W2, b2, lut);
    const int grid = 2048;         // 8 blocks/CU, 32 waves/CU (full occupancy)
    hipLaunchKernelGGL(mlp_lut_kernel, dim3(grid), dim3(256), 0, stream,
                       x, lut, out, n4);
}

// Round 3
// 235.471 us; speedup vs baseline: 1.0212x; 1.0212x over previous
//
#include <hip/hip_runtime.h>

// y = g(x) + x, g = W2^T relu(W1^T relu(x*W0+b0)+b1) + b2 is piecewise-linear
// in the scalar x. 2048-bin (slope,intercept) chord LUT over [-8,8]
// (bin width 0.0078125; kink-bin chord error ~0.01 << 0.115 threshold).
// Index is CLAMPED: edge bins extrapolate the tail lines (g is linear in the
// tails). Input is N(0,1) (|x|max ~5.4 over 2^25 samples) so clamping never
// fires on real data. LUT staged in LDS (16 KiB -> 8 blocks/CU, 32 waves/CU).
// x/out are touch-once streams -> nontemporal load/store via native clang
// vector type (HIP_vector_type is rejected by the nontemporal builtins).
//
// Session journal (measured on MI355X, window includes ~158us of harness
// re-poison fills at 85% HBM peak that no kernel change can touch):
//  R0 this kernel (AoS, x2 unroll, NT both)            : 234.6 us  <- best
//  R1 SoA LUT + plain stores                           : 237.8 us  (noise)
//  R2 x4 unroll, 4 loads in flight, NT both            : 240.5 us  (noise)
// All three are within the fill-noise band; reverting to the best-measured
// variant. Stream kernel itself is <79us (never enters top-5), memory-bound:
// LDS pipe and VALU both have ~4x slack vs the HBM stream at 6.3 TB/s.

#define NB       2048
#define LUT_LO   (-8.0f)
#define LUT_INVW (128.0f)          // NB / (HI-LO)
#define LUT_BINW (0.0078125f)      // (HI-LO)/NB

typedef float f32x4 __attribute__((ext_vector_type(4)));
typedef float f32x2 __attribute__((ext_vector_type(2)));

__device__ __forceinline__ float mlp_g(float xe,
    const float* w0, const float* b0, const float* w1,
    const float* b1, const float* w2, float b2)
{
    float h0[8];
#pragma unroll
    for (int j = 0; j < 8; ++j)
        h0[j] = fmaxf(fmaf(xe, w0[j], b0[j]), 0.0f);
    float acc = b2;
#pragma unroll
    for (int k = 0; k < 8; ++k) {
        float t = b1[k];
#pragma unroll
        for (int j = 0; j < 8; ++j)
            t = fmaf(h0[j], w1[j * 8 + k], t);
        acc = fmaf(fmaxf(t, 0.0f), w2[k], acc);
    }
    return acc;
}

__global__ __launch_bounds__(256) void build_lut_kernel(
    const float* __restrict__ W0p, const float* __restrict__ B0p,
    const float* __restrict__ W1p, const float* __restrict__ B1p,
    const float* __restrict__ W2p, const float* __restrict__ B2p,
    f32x2* __restrict__ lut)
{
    int i = blockIdx.x * blockDim.x + threadIdx.x;
    if (i >= NB) return;
    float w0[8], b0[8], b1v[8], w2[8], w1[64];
#pragma unroll
    for (int j = 0; j < 8; ++j) {
        w0[j] = W0p[j]; b0[j] = B0p[j]; b1v[j] = B1p[j]; w2[j] = W2p[j];
    }
#pragma unroll
    for (int j = 0; j < 64; ++j) w1[j] = W1p[j];
    const float b2 = B2p[0];

    float x0 = LUT_LO + (float)i * LUT_BINW;
    float x1 = x0 + LUT_BINW;
    float g0 = mlp_g(x0, w0, b0, w1, b1v, w2, b2);
    float g1 = mlp_g(x1, w0, b0, w1, b1v, w2, b2);
    float s  = (g1 - g0) * LUT_INVW;
    f32x2 sc; sc.x = s; sc.y = fmaf(-s, x0, g0);   // g(x) ~= s*x + c
    lut[i] = sc;
}

__global__ __launch_bounds__(256) void mlp_lut_kernel(
    const float* __restrict__ x,
    const f32x2* __restrict__ lut_g,
    float* __restrict__ out, int n4)
{
    __shared__ f32x2 slut[NB];   // 16 KiB -> wave-limited 8 blocks/CU
    {
        const f32x4* g4 = (const f32x4*)lut_g;
        f32x4* s4 = (f32x4*)slut;
        for (int j = threadIdx.x; j < NB / 2; j += 256)
            s4[j] = g4[j];
    }
    __syncthreads();

    const f32x4* __restrict__ x4 = (const f32x4*)x;
    f32x4* __restrict__ o4 = (f32x4*)out;

    const int stride = gridDim.x * blockDim.x;
    for (int i = blockIdx.x * blockDim.x + threadIdx.x; i < n4; i += stride) {
        f32x4 v = __builtin_nontemporal_load(&x4[i]);
        float r[4] = {v.x, v.y, v.z, v.w};
        float y[4];
#pragma unroll
        for (int e = 0; e < 4; ++e) {
            float xe = r[e];
            // idx = clamp((int)(x*128 + 1024), 0, NB-1); edge bins extrapolate
            int idx = (int)fmaf(xe, LUT_INVW, -LUT_LO * LUT_INVW);
            idx = min(max(idx, 0), NB - 1);     // expect v_med3_i32
            f32x2 si = slut[idx];
            y[e] = fmaf(si.x, xe, si.y) + xe;   // g(x) + residual
        }
        f32x4 o; o.x = y[0]; o.y = y[1]; o.z = y[2]; o.w = y[3];
        __builtin_nontemporal_store(o, &o4[i]);
    }
}

extern "C" void kernel_launch(void* const* d_in, const int* in_sizes, int n_in,
                              void* d_out, int out_size, void* d_ws, size_t ws_size,
                              hipStream_t stream) {
    const float* x  = (const float*)d_in[0];
    const float* W0 = (const float*)d_in[1];
    const float* b0 = (const float*)d_in[2];
    const float* W1 = (const float*)d_in[3];
    const float* b1 = (const float*)d_in[4];
    const float* W2 = (const float*)d_in[5];
    const float* b2 = (const float*)d_in[6];
    float* out = (float*)d_out;

    const int n4 = out_size / 4;   // 2^25 elements, divisible by 4
    f32x2* lut = (f32x2*)d_ws;     // 16 KiB scratch

    hipLaunchKernelGGL(build_lut_kernel, dim3(NB / 256), dim3(256), 0, stream,
                       W0, b0, W1, b1, W2, b2, lut);
    const int grid = 2048;         // 524288 threads -> 16 float4/thread
    hipLaunchKernelGGL(mlp_lut_kernel, dim3(grid), dim3(256), 0, stream,
                       x, lut, out, n4);
}